// Round 1
// baseline (1092.019 us; speedup 1.0000x reference)
//
#include <hip/hip_runtime.h>

// VQ nearest-neighbor: z_e [B,D] f32, codebook [K,D] f32
// -> z_q [B,D] f32 (gather), indices [B] (written as f32)
// argmin_k ||z-c_k|| == argmin_k (c_sq[k] - 2*z.c_k)   (z_sq, sqrt, clamp monotonic)

constexpr int Bn = 8192;
constexpr int Kn = 8192;
constexpr int Dn = 512;

#define BM 64
#define BN 64
#define BK 32
#define NSPLIT 4
#define LPAD 4  // LDS row pad (floats): stride 68 keeps 16B alignment for b128 reads

// ---------------- c_sq[k] = sum_d codebook[k][d]^2 ----------------
__global__ __launch_bounds__(256) void csq_kernel(const float* __restrict__ C,
                                                  float* __restrict__ csq) {
  const int wave = threadIdx.x >> 6;
  const int lane = threadIdx.x & 63;
  const int row = blockIdx.x * 4 + wave;
  const float4* p = reinterpret_cast<const float4*>(C + (size_t)row * Dn);
  float s = 0.f;
#pragma unroll
  for (int r = 0; r < 2; ++r) {
    float4 v = p[lane * 2 + r];
    s += v.x * v.x + v.y * v.y + v.z * v.z + v.w * v.w;
  }
#pragma unroll
  for (int off = 32; off; off >>= 1) s += __shfl_xor(s, off);
  if (lane == 0) csq[row] = s;
}

// ---------------- fused GEMM + running argmin ----------------
// grid: (Bn/BM) * NSPLIT blocks of 256 threads.
// Each block: 64 z-rows x (Kn/NSPLIT) codebook rows.
// partials[row*NSPLIT + split] = (best_score, best_idx_as_float)
__global__ __launch_bounds__(256) void vq_kernel(const float* __restrict__ Z,
                                                 const float* __restrict__ C,
                                                 const float* __restrict__ csq,
                                                 float2* __restrict__ partials) {
  __shared__ float As[BK][BM + LPAD];  // k-major
  __shared__ float Bs[BK][BN + LPAD];

  const int t = threadIdx.x;
  const int tx = t & 15;       // codebook-col group
  const int ty = t >> 4;       // z-row group
  const int rowBlk = blockIdx.x >> 2;
  const int split = blockIdx.x & (NSPLIT - 1);
  const int row0 = rowBlk * BM;
  const int n_begin = split * (Kn / NSPLIT);
  const int n_end = n_begin + (Kn / NSPLIT);

  // staging coords: 256 threads * 8 floats = 64x32 tile
  const int sr = t >> 3;         // 0..31
  const int sc = (t & 7) * 4;    // 0,4,..,28

  float best[4] = {1e30f, 1e30f, 1e30f, 1e30f};
  int bidx[4] = {0, 0, 0, 0};

  for (int n0 = n_begin; n0 < n_end; n0 += BN) {
    float acc[4][4] = {};
    for (int k0 = 0; k0 < Dn; k0 += BK) {
#pragma unroll
      for (int r = 0; r < 2; ++r) {
        const int m = sr + r * 32;
        float4 v = *reinterpret_cast<const float4*>(Z + (size_t)(row0 + m) * Dn + k0 + sc);
        As[sc + 0][m] = v.x; As[sc + 1][m] = v.y;
        As[sc + 2][m] = v.z; As[sc + 3][m] = v.w;
      }
#pragma unroll
      for (int r = 0; r < 2; ++r) {
        const int n = sr + r * 32;
        float4 v = *reinterpret_cast<const float4*>(C + (size_t)(n0 + n) * Dn + k0 + sc);
        Bs[sc + 0][n] = v.x; Bs[sc + 1][n] = v.y;
        Bs[sc + 2][n] = v.z; Bs[sc + 3][n] = v.w;
      }
      __syncthreads();
#pragma unroll
      for (int k = 0; k < BK; ++k) {
        float4 a = *reinterpret_cast<const float4*>(&As[k][ty * 4]);
        float4 b = *reinterpret_cast<const float4*>(&Bs[k][tx * 4]);
        acc[0][0] += a.x * b.x; acc[0][1] += a.x * b.y; acc[0][2] += a.x * b.z; acc[0][3] += a.x * b.w;
        acc[1][0] += a.y * b.x; acc[1][1] += a.y * b.y; acc[1][2] += a.y * b.z; acc[1][3] += a.y * b.w;
        acc[2][0] += a.z * b.x; acc[2][1] += a.z * b.y; acc[2][2] += a.z * b.z; acc[2][3] += a.z * b.w;
        acc[3][0] += a.w * b.x; acc[3][1] += a.w * b.y; acc[3][2] += a.w * b.z; acc[3][3] += a.w * b.w;
      }
      __syncthreads();
    }
    // score and running-min update (n ascending -> strict < keeps smallest index)
#pragma unroll
    for (int j = 0; j < 4; ++j) {
      const int n = n0 + tx * 4 + j;
      const float cs = csq[n];
#pragma unroll
      for (int i = 0; i < 4; ++i) {
        const float s = cs - 2.f * acc[i][j];
        if (s < best[i]) { best[i] = s; bidx[i] = n; }
      }
    }
  }

  // reduce (min, idx) across the 16 lanes sharing the same ty (consecutive lanes)
#pragma unroll
  for (int off = 1; off < 16; off <<= 1) {
#pragma unroll
    for (int i = 0; i < 4; ++i) {
      const float os = __shfl_xor(best[i], off);
      const int oi = __shfl_xor(bidx[i], off);
      if (os < best[i] || (os == best[i] && oi < bidx[i])) { best[i] = os; bidx[i] = oi; }
    }
  }
  if (tx == 0) {
#pragma unroll
    for (int i = 0; i < 4; ++i) {
      const int row = row0 + ty * 4 + i;
      partials[row * NSPLIT + split] = make_float2(best[i], (float)bidx[i]);
    }
  }
}

// ---------------- combine splits + gather codebook row ----------------
__global__ __launch_bounds__(128) void gather_kernel(const float* __restrict__ C,
                                                     const float2* __restrict__ partials,
                                                     float* __restrict__ zq,
                                                     float* __restrict__ idx_out) {
  const int b = blockIdx.x;
  float bs = 1e30f;
  int bi = 0;
#pragma unroll
  for (int s = 0; s < NSPLIT; ++s) {
    const float2 p = partials[b * NSPLIT + s];
    const int i = (int)p.y;
    if (p.x < bs || (p.x == bs && i < bi)) { bs = p.x; bi = i; }
  }
  const int t = threadIdx.x;
  const float4 v = *reinterpret_cast<const float4*>(C + (size_t)bi * Dn + t * 4);
  *reinterpret_cast<float4*>(zq + (size_t)b * Dn + t * 4) = v;
  if (t == 0) idx_out[b] = (float)bi;
}

extern "C" void kernel_launch(void* const* d_in, const int* in_sizes, int n_in,
                              void* d_out, int out_size, void* d_ws, size_t ws_size,
                              hipStream_t stream) {
  const float* Z = (const float*)d_in[0];   // [B, D]
  const float* C = (const float*)d_in[1];   // [K, D]
  float* out = (float*)d_out;               // [B*D] z_q then [B] indices (as f32)

  float* csq = (float*)d_ws;                                        // Kn floats
  float2* partials = (float2*)((char*)d_ws + Kn * sizeof(float));   // Bn*NSPLIT float2

  csq_kernel<<<Kn / 4, 256, 0, stream>>>(C, csq);
  vq_kernel<<<(Bn / BM) * NSPLIT, 256, 0, stream>>>(Z, C, csq, partials);
  gather_kernel<<<Bn, 128, 0, stream>>>(C, partials, out, out + (size_t)Bn * Dn);
}

// Round 2
// 535.053 us; speedup vs baseline: 2.0410x; 2.0410x over previous
//
#include <hip/hip_runtime.h>

// VQ nearest-neighbor via fp16 split-GEMM on MFMA.
// z_e [B,D] f32, codebook [K,D] f32 -> z_q [B,D] f32, indices [B] (as f32)
// argmin_k ||z-c_k||  ==  argmin_k (c_sq[k] - 2*z.c_k)
// cross computed as (Zh+Zl).(Ch+Cl) ~= Zh.Ch + Zh.Cl + Zl.Ch  (3 MFMA products,
// fp32 accumulate; dropped Zl.Cl ~ 2^-22 rel -> below fp32-native dot error)

constexpr int Bn = 8192;
constexpr int Kn = 8192;
constexpr int Dn = 512;

#define NSPL 8      // K-dim (codebook) splits across blocks
#define SLOTS 16    // NSPL * 2 (two wn column-halves per block)

using half4  = __attribute__((ext_vector_type(4)))  _Float16;
using half8  = __attribute__((ext_vector_type(8)))  _Float16;
using f32x16 = __attribute__((ext_vector_type(16))) float;

// ---------------- c_sq[k] = sum_d codebook[k][d]^2 (fp32 exact) --------------
__global__ __launch_bounds__(256) void csq_kernel(const float* __restrict__ C,
                                                  float* __restrict__ csq) {
  const int wave = threadIdx.x >> 6;
  const int lane = threadIdx.x & 63;
  const int row = blockIdx.x * 4 + wave;
  const float4* p = reinterpret_cast<const float4*>(C + (size_t)row * Dn);
  float s = 0.f;
#pragma unroll
  for (int r = 0; r < 2; ++r) {
    float4 v = p[lane * 2 + r];
    s += v.x * v.x + v.y * v.y + v.z * v.z + v.w * v.w;
  }
#pragma unroll
  for (int off = 32; off; off >>= 1) s += __shfl_xor(s, off);
  if (lane == 0) csq[row] = s;
}

// ---------------- MFMA split-fp16 GEMM + fused argmin ------------------------
// grid = (Bn/128) * NSPL blocks, 256 threads (4 waves, 2x2 wave grid).
// Block tile: 128 z-rows x 128 c-cols per pass, 8 passes (1024 cols/split).
// LDS: Ah/Al/Bh/Bl [128][64] fp16, 16KB each = 64KB, XOR-8 chunk swizzle.
__global__ __launch_bounds__(256, 2) void vq_mfma(const float* __restrict__ Z,
                                                  const float* __restrict__ C,
                                                  const float* __restrict__ csq,
                                                  float2* __restrict__ partials) {
  __shared__ _Float16 Ah[128 * 64];
  __shared__ _Float16 Al[128 * 64];
  __shared__ _Float16 Bh[128 * 64];
  __shared__ _Float16 Bl[128 * 64];

  const int t = threadIdx.x;
  const int lane = t & 63;
  const int w = t >> 6;
  const int wm = w >> 1;       // wave row-half (0..1)
  const int wn = w & 1;        // wave col-half (0..1)
  const int rowblk = blockIdx.x >> 3;
  const int split = blockIdx.x & (NSPL - 1);
  const int row0 = rowblk * 128;
  const int n_split0 = split * (Kn / NSPL);

  // staging coords: 16 lanes cover one row's 64 k-floats (4 each)
  const int srow = t >> 4;          // 0..15
  const int kc = (t & 15) * 4;      // element offset in row, 0..60
  const int chunk = kc >> 3;        // 16B chunk index 0..7
  const int pos = kc & 7;           // 0 or 4

  const int r31 = lane & 31;
  const int khalf = lane >> 5;      // which K-half of the fragment this lane holds

  float best_s = 1e30f;
  int best_i = 0;

  for (int p = 0; p < 8; ++p) {
    const int nbase = n_split0 + p * 128;
    f32x16 acc[2][2] = {};  // zero-init; indexed only with unrolled constants

    for (int kt = 0; kt < 8; ++kt) {
      const int k0 = kt * 64;
      __syncthreads();  // previous tile's reads done before overwrite
      // ---- stage: global fp32 -> (h,l) fp16 -> swizzled LDS ----
#pragma unroll
      for (int rr = 0; rr < 8; ++rr) {
        const int row = rr * 16 + srow;  // 0..127
        const int sw8 = ((chunk ^ (row & 7)) << 3) + pos;
        {
          const float4 v = *reinterpret_cast<const float4*>(
              Z + (size_t)(row0 + row) * Dn + k0 + kc);
          const _Float16 h0 = (_Float16)v.x, h1 = (_Float16)v.y;
          const _Float16 h2 = (_Float16)v.z, h3 = (_Float16)v.w;
          half4 vh = {h0, h1, h2, h3};
          half4 vl = {(_Float16)(v.x - (float)h0), (_Float16)(v.y - (float)h1),
                      (_Float16)(v.z - (float)h2), (_Float16)(v.w - (float)h3)};
          *reinterpret_cast<half4*>(Ah + row * 64 + sw8) = vh;
          *reinterpret_cast<half4*>(Al + row * 64 + sw8) = vl;
        }
        {
          const float4 v = *reinterpret_cast<const float4*>(
              C + (size_t)(nbase + row) * Dn + k0 + kc);
          const _Float16 h0 = (_Float16)v.x, h1 = (_Float16)v.y;
          const _Float16 h2 = (_Float16)v.z, h3 = (_Float16)v.w;
          half4 vh = {h0, h1, h2, h3};
          half4 vl = {(_Float16)(v.x - (float)h0), (_Float16)(v.y - (float)h1),
                      (_Float16)(v.z - (float)h2), (_Float16)(v.w - (float)h3)};
          *reinterpret_cast<half4*>(Bh + row * 64 + sw8) = vh;
          *reinterpret_cast<half4*>(Bl + row * 64 + sw8) = vl;
        }
      }
      __syncthreads();
      // ---- compute: 4 K=16 steps, 12 MFMA each ----
#pragma unroll
      for (int q = 0; q < 4; ++q) {
        half8 ahf[2], alf[2], bhf[2], blf[2];
#pragma unroll
        for (int ms = 0; ms < 2; ++ms) {
          const int row = wm * 64 + ms * 32 + r31;
          const int off = row * 64 + (((2 * q + khalf) ^ (row & 7)) << 3);
          ahf[ms] = *reinterpret_cast<const half8*>(Ah + off);
          alf[ms] = *reinterpret_cast<const half8*>(Al + off);
        }
#pragma unroll
        for (int ns = 0; ns < 2; ++ns) {
          const int row = wn * 64 + ns * 32 + r31;
          const int off = row * 64 + (((2 * q + khalf) ^ (row & 7)) << 3);
          bhf[ns] = *reinterpret_cast<const half8*>(Bh + off);
          blf[ns] = *reinterpret_cast<const half8*>(Bl + off);
        }
#pragma unroll
        for (int ms = 0; ms < 2; ++ms)
#pragma unroll
          for (int ns = 0; ns < 2; ++ns) {
            acc[ms][ns] = __builtin_amdgcn_mfma_f32_32x32x16_f16(
                ahf[ms], bhf[ns], acc[ms][ns], 0, 0, 0);
            acc[ms][ns] = __builtin_amdgcn_mfma_f32_32x32x16_f16(
                ahf[ms], blf[ns], acc[ms][ns], 0, 0, 0);
            acc[ms][ns] = __builtin_amdgcn_mfma_f32_32x32x16_f16(
                alf[ms], bhf[ns], acc[ms][ns], 0, 0, 0);
          }
      }
    }

    // ---- fused argmin epilogue for this 128-col pass ----
    // score(m,n) = csq[n] - 2*cross(m,n); C/D layout: col=lane&31,
    // row = (reg&3) + 8*(reg>>2) + 4*khalf  (per 32x32 subtile)
    const float cs0 = csq[nbase + wn * 64 + r31];
    const float cs1 = csq[nbase + wn * 64 + 32 + r31];
    const int n0i = nbase + wn * 64 + r31;
#pragma unroll
    for (int ms = 0; ms < 2; ++ms) {
#pragma unroll
      for (int r = 0; r < 16; ++r) {
        const float s0 = cs0 - 2.f * acc[ms][0][r];
        const float s1 = cs1 - 2.f * acc[ms][1][r];
        float s;
        int ni;
        if (s1 < s0) { s = s1; ni = n0i + 32; } else { s = s0; ni = n0i; }
        // reduce across the 32 columns (stays within each 32-lane half)
#pragma unroll
        for (int off = 1; off <= 16; off <<= 1) {
          const float os = __shfl_xor(s, off);
          const int oi = __shfl_xor(ni, off);
          if (os < s || (os == s && oi < ni)) { s = os; ni = oi; }
        }
        // owner lane for (khalf, ms, r) keeps the running best
        if ((lane & 15) == r && ((lane >> 4) & 1) == ms) {
          if (s < best_s || (s == best_s && ni < best_i)) { best_s = s; best_i = ni; }
        }
      }
    }
  }

  // each lane owns exactly one of the wave's 64 rows
  const int r = lane & 15;
  const int ms = (lane >> 4) & 1;
  const int h = lane >> 5;
  const int grow = row0 + wm * 64 + ms * 32 + (r & 3) + 8 * (r >> 2) + 4 * h;
  partials[grow * SLOTS + split * 2 + wn] = make_float2(best_s, (float)best_i);
}

// ---------------- combine 16 partial slots + gather codebook row -------------
__global__ __launch_bounds__(128) void gather_kernel(const float* __restrict__ C,
                                                     const float2* __restrict__ partials,
                                                     float* __restrict__ zq,
                                                     float* __restrict__ idx_out) {
  const int b = blockIdx.x;
  float bs = 1e30f;
  int bi = 0x7fffffff;
#pragma unroll
  for (int s = 0; s < SLOTS; ++s) {
    const float2 p = partials[b * SLOTS + s];
    const int i = (int)p.y;
    if (p.x < bs || (p.x == bs && i < bi)) { bs = p.x; bi = i; }
  }
  const int t = threadIdx.x;
  const float4 v = *reinterpret_cast<const float4*>(C + (size_t)bi * Dn + t * 4);
  *reinterpret_cast<float4*>(zq + (size_t)b * Dn + t * 4) = v;
  if (t == 0) idx_out[b] = (float)bi;
}

extern "C" void kernel_launch(void* const* d_in, const int* in_sizes, int n_in,
                              void* d_out, int out_size, void* d_ws, size_t ws_size,
                              hipStream_t stream) {
  const float* Z = (const float*)d_in[0];  // [B, D]
  const float* C = (const float*)d_in[1];  // [K, D]
  float* out = (float*)d_out;              // [B*D] z_q then [B] indices

  float* csq = (float*)d_ws;                                       // Kn floats
  float2* partials = (float2*)((char*)d_ws + Kn * sizeof(float));  // Bn*SLOTS float2

  csq_kernel<<<Kn / 4, 256, 0, stream>>>(C, csq);
  vq_mfma<<<(Bn / 128) * NSPL, 256, 0, stream>>>(Z, C, csq, partials);
  gather_kernel<<<Bn, 128, 0, stream>>>(C, partials, out, out + (size_t)Bn * Dn);
}

// Round 3
// 249.333 us; speedup vs baseline: 4.3798x; 2.1459x over previous
//
#include <hip/hip_runtime.h>

// VQ nearest-neighbor via fp16 split-GEMM on MFMA, pre-split + pre-tiled operands.
// z_e [B,D] f32, codebook [K,D] f32 -> z_q [B,D] f32, indices [B] (as f32)
// argmin_k ||z-c_k|| == argmin_k (c_sq[k] - 2*z.c_k)
// cross = Zh.Ch + Zh.Cl + Zl.Ch (fp32 MFMA accum; dropped Zl.Cl ~ 2^-22 rel)

constexpr int Bn = 8192;
constexpr int Kn = 8192;
constexpr int Dn = 512;

#define NSPL 8
#define SLOTS 16

using half8  = __attribute__((ext_vector_type(8)))  _Float16;
using f32x16 = __attribute__((ext_vector_type(16))) float;

// workspace layout (bytes)
#define WS_CSQ  0u
#define WS_PART (32u * 1024u)
#define WS_ZH   (2u * 1024u * 1024u)
#define WS_ZL   (10u * 1024u * 1024u)
#define WS_CH   (18u * 1024u * 1024u)
#define WS_CL   (26u * 1024u * 1024u)

typedef __attribute__((address_space(3))) void       as3_void;
typedef const __attribute__((address_space(1))) void as1_cvoid;

// Tile image (per 128-row x 32-col fp16 tile, 8KB):
//   pair = row>>1, ch8 = (4*(row&1) + (col>>3)) ^ (pair&7), pos = col&7
//   half_index = pair*64 + ch8*8 + pos
// Frag reads (32 lanes, rows r31, fixed chunk) then hit each 16B bank-slot
// 4x per 32-lane half -> near the b128 hardware floor.

// ---------------- prep: fp32 -> (h,l) fp16, tiled+swizzled ----------------
__global__ __launch_bounds__(256) void prep_kernel(const float* __restrict__ Z,
                                                   const float* __restrict__ Cb,
                                                   char* __restrict__ ws) {
  const int gid = blockIdx.x * 256 + threadIdx.x;  // 2 * 524288 threads
  const int mat = gid >> 19;                       // 0=Z, 1=C
  const int cid = gid & 524287;                    // 16B-chunk id within matrix
  const int tile = cid >> 9;                       // blk*16 + kt
  const int c = cid & 511;
  const int pair = c >> 3;
  const int ch8 = c & 7;
  const int x = ch8 ^ (pair & 7);
  const int ip = x >> 2;
  const int cc = x & 3;
  const int blk = tile >> 4;
  const int kt = tile & 15;
  const int row = blk * 128 + pair * 2 + ip;
  const int colf = kt * 32 + cc * 8;
  const float* src = (mat ? Cb : Z) + (size_t)row * Dn + colf;
  const float4 v0 = *reinterpret_cast<const float4*>(src);
  const float4 v1 = *reinterpret_cast<const float4*>(src + 4);
  const float f[8] = {v0.x, v0.y, v0.z, v0.w, v1.x, v1.y, v1.z, v1.w};
  _Float16 h[8], l[8];
#pragma unroll
  for (int j = 0; j < 8; ++j) {
    h[j] = (_Float16)f[j];
    l[j] = (_Float16)(f[j] - (float)h[j]);
  }
  const half8 vh = {h[0], h[1], h[2], h[3], h[4], h[5], h[6], h[7]};
  const half8 vl = {l[0], l[1], l[2], l[3], l[4], l[5], l[6], l[7]};
  char* hb = ws + (mat ? WS_CH : WS_ZH);
  char* lb = ws + (mat ? WS_CL : WS_ZL);
  *reinterpret_cast<half8*>(hb + (size_t)cid * 16) = vh;
  *reinterpret_cast<half8*>(lb + (size_t)cid * 16) = vl;
}

// ---------------- c_sq[k] (fp32 exact, deterministic) ----------------
__global__ __launch_bounds__(256) void csq_kernel(const float* __restrict__ C,
                                                  float* __restrict__ csq) {
  const int wave = threadIdx.x >> 6;
  const int lane = threadIdx.x & 63;
  const int row = blockIdx.x * 4 + wave;
  const float4* p = reinterpret_cast<const float4*>(C + (size_t)row * Dn);
  float s = 0.f;
#pragma unroll
  for (int r = 0; r < 2; ++r) {
    float4 v = p[lane * 2 + r];
    s += v.x * v.x + v.y * v.y + v.z * v.z + v.w * v.w;
  }
#pragma unroll
  for (int off = 32; off; off >>= 1) s += __shfl_xor(s, off);
  if (lane == 0) csq[row] = s;
}

// ---------------- MFMA GEMM + fused argmin, dbuf + global_load_lds ----------
// grid = 64 rowblks * NSPL, 256 threads (4 waves 2x2), 2 blocks/CU.
// BK=32, 16 k-tiles/pass, 8 passes of 128 codebook cols per split.
__global__ __launch_bounds__(256, 2) void vq_mfma(const char* __restrict__ ws,
                                                  const float* __restrict__ csq,
                                                  float2* __restrict__ partials) {
  __shared__ uint4 lds4[4096];  // 64KB: 2 bufs x {Ah,Al,Bh,Bl} x 8KB
  char* lds = (char*)lds4;

  const int t = threadIdx.x;
  const int lane = t & 63;
  const int w = t >> 6;
  const int wm = w >> 1, wn = w & 1;
  const int rowblk = blockIdx.x >> 3;
  const int split = blockIdx.x & 7;   // split s -> XCD s: C panel L2-resident
  const int r31 = lane & 31;
  const int khalf = lane >> 5;

  // precomputed fragment byte-offsets within an 8KB tile
  int offA[2][2], offB[2][2];
#pragma unroll
  for (int ms = 0; ms < 2; ++ms) {
    const int row = wm * 64 + ms * 32 + r31;
    const int pr = row >> 1;
#pragma unroll
    for (int q = 0; q < 2; ++q)
      offA[ms][q] = pr * 128 + ((((row & 1) << 2) + 2 * q + khalf) ^ (pr & 7)) * 16;
  }
#pragma unroll
  for (int ns = 0; ns < 2; ++ns) {
    const int row = wn * 64 + ns * 32 + r31;
    const int pr = row >> 1;
#pragma unroll
    for (int q = 0; q < 2; ++q)
      offB[ns][q] = pr * 128 + ((((row & 1) << 2) + 2 * q + khalf) ^ (pr & 7)) * 16;
  }

  // staging: wave w owns one of {Zh, Zl, Ch, Cl}
  const char* sbase = (w == 0)   ? ws + WS_ZH
                      : (w == 1) ? ws + WS_ZL
                      : (w == 2) ? ws + WS_CH
                                 : ws + WS_CL;
  const int tbaseA = rowblk * 16;
  char* const dwave = lds + w * 8192;

  auto STAGE = [&](int u, int bsel) {
    const int pp = u >> 4, kt = u & 15;
    const int tid = (w < 2) ? (tbaseA + kt) : ((split * 8 + pp) * 16 + kt);
    const char* s = sbase + (size_t)tid * 8192;
    char* d = dwave + bsel * 32768;
#pragma unroll
    for (int i = 0; i < 8; ++i)
      __builtin_amdgcn_global_load_lds(
          (as1_cvoid*)(s + i * 1024 + (size_t)lane * 16),
          (as3_void*)(d + i * 1024), 16, 0, 0);
  };

  float bs[2][16];
  int bidx[2][16];
#pragma unroll
  for (int ms = 0; ms < 2; ++ms)
#pragma unroll
    for (int r = 0; r < 16; ++r) { bs[ms][r] = 1e30f; bidx[ms][r] = 0x7fffffff; }

  STAGE(0, 0);
  asm volatile("s_waitcnt vmcnt(0)" ::: "memory");
  __syncthreads();

  for (int p = 0; p < 8; ++p) {
    const int n0i = split * 1024 + p * 128 + wn * 64 + r31;
    const float c0 = csq[n0i];        // lands during kt=0 compute
    const float c1 = csq[n0i + 32];
    f32x16 acc[2][2] = {};
    for (int kt = 0; kt < 16; ++kt) {
      const int u = p * 16 + kt;
      const int bsel = kt & 1;
      if (u + 1 < 128) STAGE(u + 1, bsel ^ 1);
      const char* Abh = lds + bsel * 32768;
      const char* Abl = Abh + 8192;
      const char* Bbh = Abh + 16384;
      const char* Bbl = Abh + 24576;
#pragma unroll
      for (int q = 0; q < 2; ++q) {
        half8 ah[2], al[2], bh[2], bl[2];
#pragma unroll
        for (int ms = 0; ms < 2; ++ms) {
          ah[ms] = *reinterpret_cast<const half8*>(Abh + offA[ms][q]);
          al[ms] = *reinterpret_cast<const half8*>(Abl + offA[ms][q]);
        }
#pragma unroll
        for (int ns = 0; ns < 2; ++ns) {
          bh[ns] = *reinterpret_cast<const half8*>(Bbh + offB[ns][q]);
          bl[ns] = *reinterpret_cast<const half8*>(Bbl + offB[ns][q]);
        }
        // 3 rounds: spaces each accumulator's 3 MFMAs 4 apart (no dep chain)
#pragma unroll
        for (int ms = 0; ms < 2; ++ms)
#pragma unroll
          for (int ns = 0; ns < 2; ++ns)
            acc[ms][ns] = __builtin_amdgcn_mfma_f32_32x32x16_f16(
                ah[ms], bh[ns], acc[ms][ns], 0, 0, 0);
#pragma unroll
        for (int ms = 0; ms < 2; ++ms)
#pragma unroll
          for (int ns = 0; ns < 2; ++ns)
            acc[ms][ns] = __builtin_amdgcn_mfma_f32_32x32x16_f16(
                ah[ms], bl[ns], acc[ms][ns], 0, 0, 0);
#pragma unroll
        for (int ms = 0; ms < 2; ++ms)
#pragma unroll
          for (int ns = 0; ns < 2; ++ns)
            acc[ms][ns] = __builtin_amdgcn_mfma_f32_32x32x16_f16(
                al[ms], bh[ns], acc[ms][ns], 0, 0, 0);
      }
      if (kt == 15) {
        // per-lane running argmin for this 128-col pass (no cross-lane work)
#pragma unroll
        for (int ms = 0; ms < 2; ++ms)
#pragma unroll
          for (int r = 0; r < 16; ++r) {
            const float s0 = c0 - 2.f * acc[ms][0][r];
            const float s1 = c1 - 2.f * acc[ms][1][r];
            float s;
            int ni;
            if (s1 < s0) { s = s1; ni = n0i + 32; } else { s = s0; ni = n0i; }
            if (s < bs[ms][r]) { bs[ms][r] = s; bidx[ms][r] = ni; }
          }
      }
      asm volatile("s_waitcnt vmcnt(0)" ::: "memory");
      __syncthreads();
    }
  }

  // one final cross-lane reduce: columns live across the 32 lanes of each khalf
  float fs = 1e30f;
  int fi = 0;
#pragma unroll
  for (int ms = 0; ms < 2; ++ms)
#pragma unroll
    for (int r = 0; r < 16; ++r) {
      float s = bs[ms][r];
      int ni = bidx[ms][r];
#pragma unroll
      for (int off = 1; off <= 16; off <<= 1) {
        const float os = __shfl_xor(s, off);
        const int oi = __shfl_xor(ni, off);
        if (os < s || (os == s && oi < ni)) { s = os; ni = oi; }
      }
      if (r31 == ms * 16 + r) { fs = s; fi = ni; }
    }
  const int msL = r31 >> 4;
  const int rL = r31 & 15;
  const int grow = rowblk * 128 + wm * 64 + msL * 32 + (rL & 3) + 8 * (rL >> 2) + 4 * khalf;
  partials[grow * SLOTS + split * 2 + wn] = make_float2(fs, (float)fi);
}

// ---------------- combine partial slots + gather codebook row ----------------
__global__ __launch_bounds__(128) void gather_kernel(const float* __restrict__ C,
                                                     const float2* __restrict__ partials,
                                                     float* __restrict__ zq,
                                                     float* __restrict__ idx_out) {
  const int b = blockIdx.x;
  float bsv = 1e30f;
  int bi = 0x7fffffff;
#pragma unroll
  for (int s = 0; s < SLOTS; ++s) {
    const float2 p = partials[b * SLOTS + s];
    const int i = (int)p.y;
    if (p.x < bsv || (p.x == bsv && i < bi)) { bsv = p.x; bi = i; }
  }
  const int t = threadIdx.x;
  const float4 v = *reinterpret_cast<const float4*>(C + (size_t)bi * Dn + t * 4);
  *reinterpret_cast<float4*>(zq + (size_t)b * Dn + t * 4) = v;
  if (t == 0) idx_out[b] = (float)bi;
}

extern "C" void kernel_launch(void* const* d_in, const int* in_sizes, int n_in,
                              void* d_out, int out_size, void* d_ws, size_t ws_size,
                              hipStream_t stream) {
  const float* Z = (const float*)d_in[0];  // [B, D]
  const float* C = (const float*)d_in[1];  // [K, D]
  float* out = (float*)d_out;              // [B*D] z_q then [B] indices

  char* ws = (char*)d_ws;                  // needs 34MB
  float* csq = (float*)(ws + WS_CSQ);
  float2* partials = (float2*)(ws + WS_PART);

  prep_kernel<<<4096, 256, 0, stream>>>(Z, C, ws);
  csq_kernel<<<Kn / 4, 256, 0, stream>>>(C, csq);
  vq_mfma<<<(Bn / 128) * NSPL, 256, 0, stream>>>(ws, csq, partials);
  gather_kernel<<<Bn, 128, 0, stream>>>(C, partials, out, out + (size_t)Bn * Dn);
}

// Round 4
// 231.477 us; speedup vs baseline: 4.7176x; 1.0771x over previous
//
#include <hip/hip_runtime.h>

// VQ nearest-neighbor via fp16 split-GEMM on MFMA, pre-split + pre-tiled operands.
// z_e [B,D] f32, codebook [K,D] f32 -> z_q [B,D] f32, indices [B] (as f32)
// argmin_k ||z-c_k|| == argmin_k (c_sq[k] - 2*z.c_k)
// cross = Zh.Ch + Zh.Cl + Zl.Ch (fp32 MFMA accum; dropped Zl.Cl ~ 2^-22 rel)
// Round 4: wave tile 64x128 (BK=16) rebalances LDS:MFMA to 1286:1536 cyc/CU,
// and 3-buffer rotation with counted vmcnt(6) (never drain) hides HBM misses.

constexpr int Bn = 8192;
constexpr int Kn = 8192;
constexpr int Dn = 512;

#define SLOTS 16

using half8  = __attribute__((ext_vector_type(8)))  _Float16;
using f32x16 = __attribute__((ext_vector_type(16))) float;

// workspace layout (bytes)
#define WS_CSQ  0u
#define WS_PART (32u * 1024u)
#define WS_ZH   (2u * 1024u * 1024u)
#define WS_ZL   (10u * 1024u * 1024u)
#define WS_CH   (18u * 1024u * 1024u)
#define WS_CL   (26u * 1024u * 1024u)

typedef __attribute__((address_space(3))) void       as3_void;
typedef const __attribute__((address_space(1))) void as1_cvoid;

// Tile images: A-tile (Z) = 128 rows x 16 halves = 4KB; B-tile (C) = 256 x 16 = 8KB.
// Within a tile: quad = row>>2, ch = (((row&3)<<1) + (col>>3)) ^ (quad&7),
// byte = quad*128 + ch*16 + (col&7)*2.  Frag b128 reads then spread across chunks.

// ---------------- prep: fp32 -> (h,l) fp16, tiled+swizzled ----------------
__global__ __launch_bounds__(256) void prep_kernel(const float* __restrict__ Z,
                                                   const float* __restrict__ Cb,
                                                   char* __restrict__ ws) {
  const int gid = blockIdx.x * 256 + threadIdx.x;  // 2 * 524288 16B-chunks
  const int mat = gid >> 19;                       // 0=Z, 1=C
  const int cid = gid & 524287;
  int row, colf;
  if (mat == 0) {
    const int tile = cid >> 8;            // rowblk*32 + kt  (2048 tiles of 4KB)
    const int quad = (cid >> 3) & 31;
    const int ch = cid & 7;
    const int x = ch ^ (quad & 7);
    row = (tile >> 5) * 128 + quad * 4 + (x >> 1);
    colf = (tile & 31) * 16 + (x & 1) * 8;
  } else {
    const int tile = cid >> 9;            // colblk*32 + kt  (1024 tiles of 8KB)
    const int quad = (cid >> 3) & 63;
    const int ch = cid & 7;
    const int x = ch ^ (quad & 7);
    row = (tile >> 5) * 256 + quad * 4 + (x >> 1);
    colf = (tile & 31) * 16 + (x & 1) * 8;
  }
  const float* src = (mat ? Cb : Z) + (size_t)row * Dn + colf;
  const float4 v0 = *reinterpret_cast<const float4*>(src);
  const float4 v1 = *reinterpret_cast<const float4*>(src + 4);
  const float f[8] = {v0.x, v0.y, v0.z, v0.w, v1.x, v1.y, v1.z, v1.w};
  _Float16 h[8], l[8];
#pragma unroll
  for (int j = 0; j < 8; ++j) {
    h[j] = (_Float16)f[j];
    l[j] = (_Float16)(f[j] - (float)h[j]);
  }
  const half8 vh = {h[0], h[1], h[2], h[3], h[4], h[5], h[6], h[7]};
  const half8 vl = {l[0], l[1], l[2], l[3], l[4], l[5], l[6], l[7]};
  char* hb = ws + (mat ? WS_CH : WS_ZH);
  char* lb = ws + (mat ? WS_CL : WS_ZL);
  *reinterpret_cast<half8*>(hb + (size_t)cid * 16) = vh;
  *reinterpret_cast<half8*>(lb + (size_t)cid * 16) = vl;
}

// ---------------- c_sq[k] (fp32 exact, deterministic) ----------------
__global__ __launch_bounds__(256) void csq_kernel(const float* __restrict__ C,
                                                  float* __restrict__ csq) {
  const int wave = threadIdx.x >> 6;
  const int lane = threadIdx.x & 63;
  const int row = blockIdx.x * 4 + wave;
  const float4* p = reinterpret_cast<const float4*>(C + (size_t)row * Dn);
  float s = 0.f;
#pragma unroll
  for (int r = 0; r < 2; ++r) {
    float4 v = p[lane * 2 + r];
    s += v.x * v.x + v.y * v.y + v.z * v.z + v.w * v.w;
  }
#pragma unroll
  for (int off = 32; off; off >>= 1) s += __shfl_xor(s, off);
  if (lane == 0) csq[row] = s;
}

// ---------------- MFMA GEMM + fused argmin -----------------------------------
// grid = 64 rowblks * 8 splits, 256 threads (4 waves, 2x2), 2 blocks/CU.
// Block tile 128x256, BK=16; per split: 4 panels of 256 cols, 32 k-tiles each.
// LDS: 3 rotating buffers x 24KB [Ah 4K | Al 4K | Bh 8K | Bl 8K].
__global__ __launch_bounds__(256, 2) void vq_mfma(const char* __restrict__ ws,
                                                  const float* __restrict__ csq,
                                                  float2* __restrict__ partials) {
  __shared__ uint4 lds4[4608];  // 72KB
  char* lds = (char*)lds4;

  const int t = threadIdx.x;
  const int lane = t & 63;
  const int w = t >> 6;
  const int wm = w >> 1, wn = w & 1;
  const int rowblk = blockIdx.x >> 3;
  const int split = blockIdx.x & 7;
  const int r31 = lane & 31;
  const int kh = lane >> 5;

  // fragment byte-offsets within a buffer
  int offA[2][2], offB[4][2];
#pragma unroll
  for (int ms = 0; ms < 2; ++ms) {
    const int row = wm * 64 + ms * 32 + r31;
    const int quad = row >> 2;
    const int base = quad * 128 + (((((row & 3) << 1) + kh) ^ (quad & 7)) << 4);
    offA[ms][0] = base;           // Ah
    offA[ms][1] = 4096 + base;    // Al
  }
#pragma unroll
  for (int ns = 0; ns < 4; ++ns) {
    const int row = wn * 128 + ns * 32 + r31;
    const int quad = row >> 2;
    const int base = quad * 128 + (((((row & 3) << 1) + kh) ^ (quad & 7)) << 4);
    offB[ns][0] = 8192 + base;    // Bh
    offB[ns][1] = 16384 + base;   // Bl
  }

  const char* ZH = ws + WS_ZH;
  const char* ZL = ws + WS_ZL;
  const char* CH = ws + WS_CH;
  const char* CL = ws + WS_CL;
  const size_t lane16 = (size_t)lane * 16 + (size_t)w * 1024;

  // stage tile u (= panel*32 + kt) into buffer bsel; 6 x 1KB per wave
  auto STAGE = [&](int u, int bsel) {
    const int kt = u & 31, panel = u >> 5;
    const size_t at = (size_t)(rowblk * 32 + kt) * 4096 + lane16;
    const size_t bt = (size_t)(((split * 4 + panel) * 32) + kt) * 8192 + lane16;
    char* d = lds + bsel * 24576 + w * 1024;
    __builtin_amdgcn_global_load_lds((as1_cvoid*)(ZH + at), (as3_void*)(d), 16, 0, 0);
    __builtin_amdgcn_global_load_lds((as1_cvoid*)(ZL + at), (as3_void*)(d + 4096), 16, 0, 0);
    __builtin_amdgcn_global_load_lds((as1_cvoid*)(CH + bt), (as3_void*)(d + 8192), 16, 0, 0);
    __builtin_amdgcn_global_load_lds((as1_cvoid*)(CH + bt + 4096), (as3_void*)(d + 12288), 16, 0, 0);
    __builtin_amdgcn_global_load_lds((as1_cvoid*)(CL + bt), (as3_void*)(d + 16384), 16, 0, 0);
    __builtin_amdgcn_global_load_lds((as1_cvoid*)(CL + bt + 4096), (as3_void*)(d + 20480), 16, 0, 0);
  };

  float bs[2][16];
  int bidx[2][16];
#pragma unroll
  for (int ms = 0; ms < 2; ++ms)
#pragma unroll
    for (int r = 0; r < 16; ++r) { bs[ms][r] = 1e30f; bidx[ms][r] = 0x7fffffff; }

  STAGE(0, 0);
  STAGE(1, 1);
  asm volatile("s_waitcnt vmcnt(6)" ::: "memory");  // tile 0 landed; tile 1 in flight
  __builtin_amdgcn_s_barrier();

  int cur = 0;  // u % 3
  for (int panel = 0; panel < 4; ++panel) {
    const int n0i = split * 1024 + panel * 256 + wn * 128 + r31;
    float cs[4];
#pragma unroll
    for (int ns = 0; ns < 4; ++ns) cs[ns] = csq[n0i + ns * 32];
    f32x16 acc[2][4] = {};

    for (int kt = 0; kt < 32; ++kt) {
      const int u = panel * 32 + kt;
      const int nx2 = cur >= 1 ? cur - 1 : cur + 2;  // (u+2) % 3
      if (u + 2 < 128) STAGE(u + 2, nx2);

      const char* Lb = lds + cur * 24576;
      half8 ah[2], al[2], bh[4], bl[4];
#pragma unroll
      for (int ms = 0; ms < 2; ++ms) {
        ah[ms] = *reinterpret_cast<const half8*>(Lb + offA[ms][0]);
        al[ms] = *reinterpret_cast<const half8*>(Lb + offA[ms][1]);
      }
#pragma unroll
      for (int ns = 0; ns < 4; ++ns) {
        bh[ns] = *reinterpret_cast<const half8*>(Lb + offB[ns][0]);
        bl[ns] = *reinterpret_cast<const half8*>(Lb + offB[ns][1]);
      }
      // 3 product rounds of 8 MFMA: each accumulator revisited every 8 instrs
#pragma unroll
      for (int ms = 0; ms < 2; ++ms)
#pragma unroll
        for (int ns = 0; ns < 4; ++ns)
          acc[ms][ns] = __builtin_amdgcn_mfma_f32_32x32x16_f16(
              ah[ms], bh[ns], acc[ms][ns], 0, 0, 0);
#pragma unroll
      for (int ms = 0; ms < 2; ++ms)
#pragma unroll
        for (int ns = 0; ns < 4; ++ns)
          acc[ms][ns] = __builtin_amdgcn_mfma_f32_32x32x16_f16(
              ah[ms], bl[ns], acc[ms][ns], 0, 0, 0);
#pragma unroll
      for (int ms = 0; ms < 2; ++ms)
#pragma unroll
        for (int ns = 0; ns < 4; ++ns)
          acc[ms][ns] = __builtin_amdgcn_mfma_f32_32x32x16_f16(
              al[ms], bh[ns], acc[ms][ns], 0, 0, 0);

      // counted wait: tile u+1 (issued one iter ago) must land; u+2's 6 stay in flight
      if (u < 126)
        asm volatile("s_waitcnt vmcnt(6) lgkmcnt(0)" ::: "memory");
      else
        asm volatile("s_waitcnt vmcnt(0) lgkmcnt(0)" ::: "memory");
      __builtin_amdgcn_s_barrier();
      cur = cur == 2 ? 0 : cur + 1;
    }

    // fold this panel into the per-lane running best
#pragma unroll
    for (int ms = 0; ms < 2; ++ms)
#pragma unroll
      for (int r = 0; r < 16; ++r) {
        float s = cs[0] - 2.f * acc[ms][0][r];
        int ni = n0i;
#pragma unroll
        for (int ns = 1; ns < 4; ++ns) {
          const float s2 = cs[ns] - 2.f * acc[ms][ns][r];
          if (s2 < s) { s = s2; ni = n0i + ns * 32; }
        }
        if (s < bs[ms][r]) { bs[ms][r] = s; bidx[ms][r] = ni; }
      }
  }

  // final cross-lane reduce (columns live across the 32 lanes of each khalf)
  float fs = 1e30f;
  int fi = 0;
#pragma unroll
  for (int ms = 0; ms < 2; ++ms)
#pragma unroll
    for (int r = 0; r < 16; ++r) {
      float s = bs[ms][r];
      int ni = bidx[ms][r];
#pragma unroll
      for (int off = 1; off <= 16; off <<= 1) {
        const float os = __shfl_xor(s, off);
        const int oi = __shfl_xor(ni, off);
        if (os < s || (os == s && oi < ni)) { s = os; ni = oi; }
      }
      if (r31 == ms * 16 + r) { fs = s; fi = ni; }
    }
  const int msL = r31 >> 4;
  const int rL = r31 & 15;
  const int grow = rowblk * 128 + wm * 64 + msL * 32 + (rL & 3) + 8 * (rL >> 2) + 4 * kh;
  partials[grow * SLOTS + split * 2 + wn] = make_float2(fs, (float)fi);
}

// ---------------- combine partial slots + gather codebook row ----------------
__global__ __launch_bounds__(128) void gather_kernel(const float* __restrict__ C,
                                                     const float2* __restrict__ partials,
                                                     float* __restrict__ zq,
                                                     float* __restrict__ idx_out) {
  const int b = blockIdx.x;
  float bsv = 1e30f;
  int bi = 0x7fffffff;
#pragma unroll
  for (int s = 0; s < SLOTS; ++s) {
    const float2 p = partials[b * SLOTS + s];
    const int i = (int)p.y;
    if (p.x < bsv || (p.x == bsv && i < bi)) { bsv = p.x; bi = i; }
  }
  const int t = threadIdx.x;
  const float4 v = *reinterpret_cast<const float4*>(C + (size_t)bi * Dn + t * 4);
  *reinterpret_cast<float4*>(zq + (size_t)b * Dn + t * 4) = v;
  if (t == 0) idx_out[b] = (float)bi;
}

extern "C" void kernel_launch(void* const* d_in, const int* in_sizes, int n_in,
                              void* d_out, int out_size, void* d_ws, size_t ws_size,
                              hipStream_t stream) {
  const float* Z = (const float*)d_in[0];  // [B, D]
  const float* C = (const float*)d_in[1];  // [K, D]
  float* out = (float*)d_out;              // [B*D] z_q then [B] indices

  char* ws = (char*)d_ws;                  // needs 34MB
  float* csq = (float*)(ws + WS_CSQ);
  float2* partials = (float2*)(ws + WS_PART);

  prep_kernel<<<4096, 256, 0, stream>>>(Z, C, ws);
  csq_kernel<<<Kn / 4, 256, 0, stream>>>(C, csq);
  vq_mfma<<<(Bn / 128) * 8, 256, 0, stream>>>(ws, csq, partials);
  gather_kernel<<<Bn, 128, 0, stream>>>(C, partials, out, out + (size_t)Bn * Dn);
}